// Round 7
// baseline (652.611 us; speedup 1.0000x reference)
//
#include <hip/hip_runtime.h>
#include <hip/hip_bf16.h>

// Continuous convolution, single-pass fused design (round 7):
//   WG = 4 voxels (128 edges), 512 threads, LDS 54.0 KB -> 3 WG/CU (24 waves).
//   r7 changes vs r6:
//   (1) feats gather via global_load_lds (16B/lane) into a 16KB LDS stage:
//       fire-and-forget, all 128 rows in flight per WG independent of VGPR
//       allocation (r3-r6 invariant: VGPR=28 => compiler serialized gathers,
//       ~4 lines in flight per CU, 330 GB/s latency-bound).
//   (2) 3 WG/CU (LDS trimmed: 16-word pad, fbase folded into stage region),
//       launch_bounds(512,6) gives regalloc room (<=84 VGPR).
//   (3) W fragments double-buffered across the 8-bin MFMA loop.
//   Contraction: bf16 hi/lo split MFMA (3 products), f32-exact to ~2^-16.

typedef unsigned short u16;
typedef unsigned int   u32;
typedef __attribute__((ext_vector_type(4))) float f32x4;
typedef __attribute__((ext_vector_type(8))) short short8;

#define NOUT    65536
#define VX      4               // voxels per WG
#define THREADS 512
#define EPW     128             // edges per WG
#define NWG     (NOUT / VX)     // 16384
#define BSTRIDE 2064            // f32 words per voxel (64*32 + 16 pad)
#define VROWB   (BSTRIDE * 4)   // 8256 bytes
#define BL_BYTES (VX * VROWB)   // 33024

// LDS carve (bytes):
#define OFF_FS  BL_BYTES              // fstage [128][32] f32 (fbase in word 0 pre-stage)
#define OFF_W   (OFF_FS + 16384)      // wls [8][128] f32  (alias Yp 4KB)
#define OFF_BCA (OFF_W + 4096)        // bca [128] u32 (bb | mask<<16 | nc<<24)
#define OFF_DEN (OFF_BCA + 512)       // den [4] f32
#define SMEM_BYTES (OFF_DEN + 16)     // 54032  (3 per CU even at 1KB granule)

// ---- prep: pack W (2048x32 f32) into MFMA B-fragment order, bf16 hi/lo ----
// wpk[tb][bin][lane][j] u16, tb: 0=hi d0-15, 1=lo d0-15, 2=hi d16-31, 3=lo.
// Lane l supplies B[kappa = bin*32 + (l>>4)*8 + j][d = (l&15) + 16*(tb>>1)].
__global__ void prep_w_kernel(const float* __restrict__ W,
                              u16* __restrict__ wpk) {
  int id  = blockIdx.x * 256 + threadIdx.x;   // 0..131071
  int j   = id & 7;
  int l   = (id >> 3) & 63;
  int bin = (id >> 9) & 63;
  int tb  = id >> 15;                         // 0..3
  int kap = (bin << 5) + ((l >> 4) << 3) + j;
  int d   = (l & 15) + ((tb >> 1) << 4);
  float w = W[kap * 32 + d];
  unsigned u = __float_as_uint(w);
  u16 val;
  if (tb & 1) {
    float rem = w - __uint_as_float(u & 0xFFFF0000u);   // exact residual
    val = (u16)(__float_as_uint(rem) >> 16);
  } else {
    val = (u16)(u >> 16);                               // truncated bf16
  }
  wpk[id] = val;
}

__launch_bounds__(THREADS, 6)   // 24 waves/CU (3 WGs), VGPR budget ~84
__global__ void cconv_kernel(const float* __restrict__ feats,
                             const float* __restrict__ inp_points,
                             const float* __restrict__ out_points,
                             const float* __restrict__ out_extents,
                             const float* __restrict__ scale_compat,
                             const int*   __restrict__ nbr_idx,
                             const int*   __restrict__ row_splits,
                             const float* __restrict__ nbr_dist,
                             const float* __restrict__ bias,
                             const u16*   __restrict__ wpk,
                             float*       __restrict__ out) {
  extern __shared__ __align__(16) char smem[];
  float* fstage = (float*)(smem + OFF_FS);
  float* wls    = (float*)(smem + OFF_W);
  float* Yp     = wls;                        // alias after scatter done
  u32*   bca    = (u32*)(smem + OFF_BCA);
  float* den    = (float*)(smem + OFF_DEN);

  const int tid  = threadIdx.x;
  const int wg   = blockIdx.x;
  const int lane = tid & 63;
  const int wv   = tid >> 6;                  // wave 0..7

  // ---- geometry: one edge per thread (threads 0..127) ----
  if (tid < EPW) {
    const bool is64 = (row_splits[1] == 0);   // int32 view of int64 splits
    int e  = tid;
    int v  = e >> 5;
    int gv = (wg << 2) + v;
    int ge = (wg << 7) + e;
    int idx = nbr_idx[is64 ? (ge << 1) : ge];
    float dist = nbr_dist[ge];
    float sc   = scale_compat[ge];
    float om = 1.f - dist * dist;
    om = fminf(fmaxf(om, 0.f), 1.f);
    float a = sc * om * om * om;
    float inv = 2.f / out_extents[0];
    float ox = out_points[gv * 3 + 0];
    float oy = out_points[gv * 3 + 1];
    float oz = out_points[gv * 3 + 2];
    float rx = (inp_points[idx * 3 + 0] - ox) * inv;
    float ry = (inp_points[idx * 3 + 1] - oy) * inv;
    float rz = (inp_points[idx * 3 + 2] - oz) * inv;
    float n2   = sqrtf(rx * rx + ry * ry + rz * rz + 1e-12f);
    float ninf = fmaxf(fabsf(rx), fmaxf(fabsf(ry), fabsf(rz)));
    float scl  = (ninf > 1e-8f) ? (n2 / ninf) : 0.f;
    float cx = fminf(fmaxf(rx * scl, -1.f), 1.f);
    float cy = fminf(fmaxf(ry * scl, -1.f), 1.f);
    float cz = fminf(fmaxf(rz * scl, -1.f), 1.f);
    float ux = fminf(fmaxf((cx + 1.f) * 1.5f, 0.f), 3.f);
    float uy = fminf(fmaxf((cy + 1.f) * 1.5f, 0.f), 3.f);
    float uz = fminf(fmaxf((cz + 1.f) * 1.5f, 0.f), 3.f);
    float fx = fminf(floorf(ux), 2.f);
    float fy = fminf(floorf(uy), 2.f);
    float fz = fminf(floorf(uz), 2.f);
    float tx = ux - fx, ty = uy - fy, tz = uz - fz;
    int ix = (int)fx, iy = (int)fy, iz = (int)fz;
    float X1 = tx * a, X0 = a - X1;           // fold importance into x weights
    float Y1 = ty,     Y0 = 1.f - ty;
    float Z1 = tz,     Z0 = 1.f - tz;
    float p00 = X0 * Y0, p01 = X0 * Y1, p10 = X1 * Y0, p11 = X1 * Y1;
    float wc[8];
    wc[0] = p00 * Z0; wc[1] = p00 * Z1; wc[2] = p01 * Z0; wc[3] = p01 * Z1;
    wc[4] = p10 * Z0; wc[5] = p10 * Z1; wc[6] = p11 * Z0; wc[7] = p11 * Z1;
    int kb = (ix * 4 + iy) * 4 + iz;          // base bin (<=42)
    u32 bb = (u32)(v * VROWB + (kb << 7));    // <= 30144, fits 16 bits
    int nc = 0; u32 mask = 0;
    #pragma unroll
    for (int k = 0; k < 8; ++k) {
      if (wc[k] != 0.f) {
        wls[nc * EPW + e] = wc[k];
        mask |= (1u << k);
        ++nc;
      }
    }
    bca[e] = bb | (mask << 16) | ((u32)nc << 24);
    *(int*)&fstage[e << 5] = idx;             // feats row idx, pre-stage slot
    // per-voxel denom: 32 lanes = 1 voxel, shuffle reduction
    float s = a;
    s += __shfl_xor(s, 1);
    s += __shfl_xor(s, 2);
    s += __shfl_xor(s, 4);
    s += __shfl_xor(s, 8);
    s += __shfl_xor(s, 16);
    if ((lane & 31) == 0) den[v] = s;
  }
  __syncthreads();

  // ---- stage feats rows into LDS: fire-and-forget, 16B per lane ----
  // Round rd: thread t handles row r = rd*64 + t/8, 16B chunk k = t&7.
  // LDS dest = fstage + r*128B + k*16B = wave_base + lane*16 (linear). The
  // row-idx read (own wave's rows only) completes before issue via lgkmcnt.
  {
    #pragma unroll
    for (int rd = 0; rd < 2; ++rd) {
      int r = (rd << 6) + (tid >> 3);
      int k = tid & 7;
      int idx = *(const int*)&fstage[r << 5];
      const float* g = feats + (idx << 5) + (k << 2);
      __builtin_amdgcn_global_load_lds(
          (const __attribute__((address_space(1))) void*)(const void*)g,
          (__attribute__((address_space(3))) void*)(void*)&fstage[(r << 5) + (k << 2)],
          16, 0, 0);
    }
  }

  // ---- zero B tile while the stage is in flight (pure LDS) ----
  {
    f32x4 z = {0.f, 0.f, 0.f, 0.f};
    for (int i = tid; i < (BL_BYTES / 16); i += THREADS)
      ((f32x4*)smem)[i] = z;
  }
  __syncthreads();   // drains vmcnt(0): fstage complete; B zero visible

  // ---- scatter: lane=channel, half-wave=edge row; feats from LDS ----
  {
    const int c  = tid & 31;
    const int e0 = tid >> 5;                  // 0..15
    #pragma unroll
    for (int it = 0; it < 8; ++it) {
      int   e    = (it << 4) + e0;
      u32   m    = bca[e];
      float f    = fstage[(e << 5) + c];      // banks 0..31, 2-way = free
      u32   base = (m & 0xFFFFu) + ((u32)c << 2);
      u32   mask = (m >> 16) & 0xFFu;
      int   nc   = (int)(m >> 24);
      for (int j = 0; j < nc; ++j) {          // ~2-3 iters, uniform per edge
        float w = wls[j * EPW + e];           // broadcast within half-wave
        int   k = __builtin_ctz(mask);
        mask &= mask - 1;
        u32 d = ((k & 1) << 7) | ((k & 2) << 8) | ((k & 4) << 9);
        atomicAdd((float*)(smem + base + d), w * f);
      }
    }
  }
  __syncthreads();

  // ---- MFMA contraction: wave wv owns bins [8*wv, 8*wv+8) ----
  f32x4 acc0 = {0.f, 0.f, 0.f, 0.f};          // cout 0..15
  f32x4 acc1 = {0.f, 0.f, 0.f, 0.f};          // cout 16..31
  {
    const short8* wp = (const short8*)wpk;    // [4][64][64] fragments
    int v16 = lane & 15;                      // A row (rows 4-15 dup of 0-3)
    int q   = lane >> 4;
    const char* arow = smem + (size_t)(v16 & 3) * VROWB;
    const int bin0 = wv << 3;
    short8 wbA[4], wbB[4];
    #pragma unroll
    for (int t2 = 0; t2 < 4; ++t2)            // preload bin0 fragments
      wbA[t2] = wp[((t2 * 64 + bin0) << 6) + lane];
    #pragma unroll
    for (int b = 0; b < 8; ++b) {             // full unroll: static wb index
      int bin = bin0 + b;
      short8* cur = (b & 1) ? wbB : wbA;
      short8* nxt = (b & 1) ? wbA : wbB;
      if (b < 7) {
        #pragma unroll
        for (int t2 = 0; t2 < 4; ++t2)        // prefetch next bin under MFMA
          nxt[t2] = wp[((t2 * 64 + bin + 1) << 6) + lane];
      }
      const float* ap = (const float*)(arow + (bin << 7) + (q << 5));
      f32x4 a0 = *(const f32x4*)ap;           // ch k0..k0+3
      f32x4 a1 = *(const f32x4*)(ap + 4);     // ch k0+4..k0+7
      short8 ahi, alo;
      #pragma unroll
      for (int j = 0; j < 4; ++j) {
        unsigned u0 = __float_as_uint(a0[j]);
        ahi[j] = (short)(u0 >> 16);
        float r0 = a0[j] - __uint_as_float(u0 & 0xFFFF0000u);
        alo[j] = (short)(__float_as_uint(r0) >> 16);
        unsigned u1 = __float_as_uint(a1[j]);
        ahi[j + 4] = (short)(u1 >> 16);
        float r1 = a1[j] - __uint_as_float(u1 & 0xFFFF0000u);
        alo[j + 4] = (short)(__float_as_uint(r1) >> 16);
      }
      acc0 = __builtin_amdgcn_mfma_f32_16x16x32_bf16(ahi, cur[0], acc0, 0, 0, 0);
      acc0 = __builtin_amdgcn_mfma_f32_16x16x32_bf16(ahi, cur[1], acc0, 0, 0, 0);
      acc0 = __builtin_amdgcn_mfma_f32_16x16x32_bf16(alo, cur[0], acc0, 0, 0, 0);
      acc1 = __builtin_amdgcn_mfma_f32_16x16x32_bf16(ahi, cur[2], acc1, 0, 0, 0);
      acc1 = __builtin_amdgcn_mfma_f32_16x16x32_bf16(ahi, cur[3], acc1, 0, 0, 0);
      acc1 = __builtin_amdgcn_mfma_f32_16x16x32_bf16(alo, cur[2], acc1, 0, 0, 0);
    }
  }

  // ---- per-wave partials: valid C rows 0..3 in lanes 0..15, regs 0..3 ----
  // C/D layout: col = lane&15 (cout), row = (lane>>4)*4 + reg (voxel)
  if (lane < 16) {
    float* yp = Yp + (wv << 7);               // 4 v x 32 d per wave
    #pragma unroll
    for (int r = 0; r < 4; ++r) {
      yp[r * 32 + lane]      = acc0[r];
      yp[r * 32 + 16 + lane] = acc1[r];
    }
  }
  __syncthreads();

  // ---- reduce 8 wave-partials, normalize, bias, relu, store ----
  if (tid < EPW) {
    float s = 0.f;
    #pragma unroll
    for (int w = 0; w < 8; ++w) s += Yp[(w << 7) + tid];
    int v = tid >> 5;
    int d = tid & 31;
    float dn = fmaxf(den[v], 1e-8f);
    float y = s / dn + bias[d];
    out[(wg << 7) + tid] = fmaxf(y, 0.f);
  }
}

extern "C" void kernel_launch(void* const* d_in, const int* in_sizes, int n_in,
                              void* d_out, int out_size, void* d_ws, size_t ws_size,
                              hipStream_t stream) {
  const float* feats        = (const float*)d_in[0];
  const float* inp_points   = (const float*)d_in[1];
  const float* out_points   = (const float*)d_in[2];
  const float* out_extents  = (const float*)d_in[3];
  const float* scale_compat = (const float*)d_in[4];
  const int*   nbr_idx      = (const int*)d_in[5];
  const int*   row_splits   = (const int*)d_in[6];
  const float* nbr_dist     = (const float*)d_in[7];
  const float* W            = (const float*)d_in[8];
  const float* bias         = (const float*)d_in[9];

  u16* wpk = (u16*)d_ws;                // [4][64][64][8] u16 = 256 KiB

  static_assert(SMEM_BYTES <= 54613, "LDS over 3-per-CU budget");
  (void)hipFuncSetAttribute((const void*)cconv_kernel,
                            hipFuncAttributeMaxDynamicSharedMemorySize,
                            SMEM_BYTES);

  prep_w_kernel<<<512, 256, 0, stream>>>(W, wpk);
  cconv_kernel<<<NWG, THREADS, SMEM_BYTES, stream>>>(
      feats, inp_points, out_points, out_extents, scale_compat, nbr_idx,
      row_splits, nbr_dist, bias, wpk, (float*)d_out);
}

// Round 8
// 628.050 us; speedup vs baseline: 1.0391x; 1.0391x over previous
//
#include <hip/hip_runtime.h>
#include <hip/hip_bf16.h>
#include <hip/hip_fp16.h>

// Continuous convolution, single-pass fused design (round 8 = r6 + fp16 feats):
//   Evidence r3-r7: five gather structures all land at ~650us = FETCH/320GB/s
//   -> memory-system wall for random 64-128B requests. Fix: repack feats to
//   fp16 once per launch (16.8MB in d_ws) so each edge's row is ONE 64B line
//   instead of two -> halves both bytes and line count of the only
//   HBM-random stream. Accuracy: fp16 feats adds ~1e-3 abs on y (budget
//   7.66e-3, current usage 1.95e-3). B accum stays f32; contraction stays
//   bf16 hi/lo split MFMA (3 products) vs pre-packed W^T fragment tables.
//   Fallback to f32 feats if ws_size is too small for the fp16 copy.

typedef unsigned short u16;
typedef unsigned int   u32;
typedef __attribute__((ext_vector_type(4))) float f32x4;
typedef __attribute__((ext_vector_type(8))) short short8;

#define NOUT    65536
#define VX      4               // voxels per WG
#define THREADS 512
#define EPW     128             // edges per WG
#define NWG     (NOUT / VX)     // 16384
#define BSTRIDE 2052            // f32 words per voxel (64 bins * 32 ch + 4 pad)
#define VROWB   (BSTRIDE * 4)   // 8208 bytes
#define BL_BYTES (VX * VROWB)   // 32832

// LDS carve (bytes):
#define OFF_W   BL_BYTES              // wls [8][128] f32  (alias Yp 4KB)
#define OFF_BCA (OFF_W + 8*EPW*4)     // bca [128] u32 (bb | mask<<16 | nc<<24)
#define OFF_FB  (OFF_BCA + EPW*4)     // fbase [128] int
#define OFF_DEN (OFF_FB + EPW*4)      // den [4] f32
#define SMEM_BYTES (OFF_DEN + 16)     // 37968 -> 4 WG/CU

#define N_IN    262144
#define FH_ELEMS (N_IN * 32)

// ---- prep: pack W (2048x32 f32) into MFMA B-fragment order, bf16 hi/lo ----
// wpk[tb][bin][lane][j] u16, tb: 0=hi d0-15, 1=lo d0-15, 2=hi d16-31, 3=lo.
// Lane l supplies B[kappa = bin*32 + (l>>4)*8 + j][d = (l&15) + 16*(tb>>1)].
__global__ void prep_w_kernel(const float* __restrict__ W,
                              u16* __restrict__ wpk) {
  int id  = blockIdx.x * 256 + threadIdx.x;   // 0..131071
  int j   = id & 7;
  int l   = (id >> 3) & 63;
  int bin = (id >> 9) & 63;
  int tb  = id >> 15;                         // 0..3
  int kap = (bin << 5) + ((l >> 4) << 3) + j;
  int d   = (l & 15) + ((tb >> 1) << 4);
  float w = W[kap * 32 + d];
  unsigned u = __float_as_uint(w);
  u16 val;
  if (tb & 1) {
    float rem = w - __uint_as_float(u & 0xFFFF0000u);   // exact residual
    val = (u16)(__float_as_uint(rem) >> 16);
  } else {
    val = (u16)(u >> 16);                               // truncated bf16
  }
  wpk[id] = val;
}

// ---- prep: feats f32 -> fp16 (RTNE), vectorized 4-wide ----
__global__ void prep_f_kernel(const float* __restrict__ F,
                              __half* __restrict__ Fh) {
  int i = blockIdx.x * 256 + threadIdx.x;     // 0 .. FH_ELEMS/4-1
  f32x4 v = ((const f32x4*)F)[i];
  ushort4 h;
  h.x = __half_as_ushort(__float2half(v[0]));
  h.y = __half_as_ushort(__float2half(v[1]));
  h.z = __half_as_ushort(__float2half(v[2]));
  h.w = __half_as_ushort(__float2half(v[3]));
  ((ushort4*)Fh)[i] = h;
}

template <bool FP16F>
__launch_bounds__(THREADS, 8)   // VGPR<=64 so 4 WGs/CU fit wave slots
__global__ void cconv_kernel(const float* __restrict__ feats,
                             const __half* __restrict__ feats_h,
                             const float* __restrict__ inp_points,
                             const float* __restrict__ out_points,
                             const float* __restrict__ out_extents,
                             const float* __restrict__ scale_compat,
                             const int*   __restrict__ nbr_idx,
                             const int*   __restrict__ row_splits,
                             const float* __restrict__ nbr_dist,
                             const float* __restrict__ bias,
                             const u16*   __restrict__ wpk,
                             float*       __restrict__ out) {
  extern __shared__ __align__(16) char smem[];
  float* wls   = (float*)(smem + OFF_W);
  float* Yp    = wls;                         // alias after scatter done
  u32*   bca   = (u32*)(smem + OFF_BCA);
  int*   fbase = (int*)(smem + OFF_FB);
  float* den   = (float*)(smem + OFF_DEN);

  const int tid  = threadIdx.x;
  const int wg   = blockIdx.x;
  const int lane = tid & 63;
  const int wv   = tid >> 6;                  // wave 0..7

  // ---- zero B tile (all threads) ----
  {
    f32x4 z = {0.f, 0.f, 0.f, 0.f};
    for (int i = tid; i < (BL_BYTES / 16); i += THREADS)
      ((f32x4*)smem)[i] = z;
  }

  // ---- geometry: one edge per thread (threads 0..127) ----
  if (tid < EPW) {
    const bool is64 = (row_splits[1] == 0);   // int32 view of int64 splits
    int e  = tid;
    int v  = e >> 5;
    int gv = (wg << 2) + v;
    int ge = (wg << 7) + e;
    int idx = nbr_idx[is64 ? (ge << 1) : ge];
    float dist = nbr_dist[ge];
    float sc   = scale_compat[ge];
    float om = 1.f - dist * dist;
    om = fminf(fmaxf(om, 0.f), 1.f);
    float a = sc * om * om * om;
    float inv = 2.f / out_extents[0];
    float ox = out_points[gv * 3 + 0];
    float oy = out_points[gv * 3 + 1];
    float oz = out_points[gv * 3 + 2];
    float rx = (inp_points[idx * 3 + 0] - ox) * inv;
    float ry = (inp_points[idx * 3 + 1] - oy) * inv;
    float rz = (inp_points[idx * 3 + 2] - oz) * inv;
    float n2   = sqrtf(rx * rx + ry * ry + rz * rz + 1e-12f);
    float ninf = fmaxf(fabsf(rx), fmaxf(fabsf(ry), fabsf(rz)));
    float scl  = (ninf > 1e-8f) ? (n2 / ninf) : 0.f;
    float cx = fminf(fmaxf(rx * scl, -1.f), 1.f);
    float cy = fminf(fmaxf(ry * scl, -1.f), 1.f);
    float cz = fminf(fmaxf(rz * scl, -1.f), 1.f);
    float ux = fminf(fmaxf((cx + 1.f) * 1.5f, 0.f), 3.f);
    float uy = fminf(fmaxf((cy + 1.f) * 1.5f, 0.f), 3.f);
    float uz = fminf(fmaxf((cz + 1.f) * 1.5f, 0.f), 3.f);
    float fx = fminf(floorf(ux), 2.f);
    float fy = fminf(floorf(uy), 2.f);
    float fz = fminf(floorf(uz), 2.f);
    float tx = ux - fx, ty = uy - fy, tz = uz - fz;
    int ix = (int)fx, iy = (int)fy, iz = (int)fz;
    float X1 = tx * a, X0 = a - X1;           // fold importance into x weights
    float Y1 = ty,     Y0 = 1.f - ty;
    float Z1 = tz,     Z0 = 1.f - tz;
    float p00 = X0 * Y0, p01 = X0 * Y1, p10 = X1 * Y0, p11 = X1 * Y1;
    float wc[8];
    wc[0] = p00 * Z0; wc[1] = p00 * Z1; wc[2] = p01 * Z0; wc[3] = p01 * Z1;
    wc[4] = p10 * Z0; wc[5] = p10 * Z1; wc[6] = p11 * Z0; wc[7] = p11 * Z1;
    int kb = (ix * 4 + iy) * 4 + iz;          // base bin (<=42)
    u32 bb = (u32)(v * VROWB + (kb << 7));    // < 32768
    int nc = 0; u32 mask = 0;
    #pragma unroll
    for (int k = 0; k < 8; ++k) {
      if (wc[k] != 0.f) {
        wls[nc * EPW + e] = wc[k];
        mask |= (1u << k);
        ++nc;
      }
    }
    bca[e]   = bb | (mask << 16) | ((u32)nc << 24);
    fbase[e] = idx << 5;
    // per-voxel denom: half-wave (32 lanes = 1 voxel) shuffle reduction
    float s = a;
    s += __shfl_xor(s, 1);
    s += __shfl_xor(s, 2);
    s += __shfl_xor(s, 4);
    s += __shfl_xor(s, 8);
    s += __shfl_xor(s, 16);
    if ((lane & 31) == 0) den[v] = s;
  }
  __syncthreads();

  // ---- scatter: lane=channel, half-wave=edge row; 8 edges per thread ----
  {
    const int c  = tid & 31;                  // channel
    const int e0 = tid >> 5;                  // 0..15
    u32 bcn[8]; int fbs[8]; float fg[8];
    #pragma unroll
    for (int it = 0; it < 8; ++it) {
      int e = (it << 4) + e0;
      bcn[it] = bca[e];
      fbs[it] = fbase[e];
    }
    if (FP16F) {
      #pragma unroll
      for (int it = 0; it < 8; ++it)          // 64B row per half-wave: 1 line
        fg[it] = __half2float(feats_h[fbs[it] + c]);
    } else {
      #pragma unroll
      for (int it = 0; it < 8; ++it)
        fg[it] = feats[fbs[it] + c];
    }
    #pragma unroll
    for (int it = 0; it < 8; ++it) {
      int   e    = (it << 4) + e0;
      u32   m    = bcn[it];
      u32   base = (m & 0xFFFFu) + ((u32)c << 2);
      u32   mask = (m >> 16) & 0xFFu;
      int   nc   = (int)(m >> 24);
      float f    = fg[it];
      for (int j = 0; j < nc; ++j) {          // ~2-3 iters, uniform per edge
        float w = wls[j * EPW + e];           // broadcast within half-wave
        int   k = __builtin_ctz(mask);
        mask &= mask - 1;
        u32 d = ((k & 1) << 7) | ((k & 2) << 8) | ((k & 4) << 9);
        atomicAdd((float*)(smem + base + d), w * f);  // banks 0..31, <=2-way
      }
    }
  }
  __syncthreads();

  // ---- MFMA contraction: wave wv owns bins [8*wv, 8*wv+8) ----
  f32x4 acc0 = {0.f, 0.f, 0.f, 0.f};          // cout 0..15
  f32x4 acc1 = {0.f, 0.f, 0.f, 0.f};          // cout 16..31
  {
    const short8* wp = (const short8*)wpk;    // [4][64][64] fragments
    int v16 = lane & 15;                      // A row (rows 4-15 dup of 0-3)
    int q   = lane >> 4;
    const char* arow = smem + (size_t)(v16 & 3) * VROWB;
    #pragma unroll
    for (int b = 0; b < 8; ++b) {
      int bin = (wv << 3) + b;
      // coalesced 1KB-burst B-fragment loads (L2-resident)
      short8 w0h = wp[((0 * 64 + bin) << 6) + lane];
      short8 w0l = wp[((1 * 64 + bin) << 6) + lane];
      short8 w1h = wp[((2 * 64 + bin) << 6) + lane];
      short8 w1l = wp[((3 * 64 + bin) << 6) + lane];
      const float* ap = (const float*)(arow + (bin << 7) + (q << 5));
      f32x4 a0 = *(const f32x4*)ap;           // ch k0..k0+3
      f32x4 a1 = *(const f32x4*)(ap + 4);     // ch k0+4..k0+7
      short8 ahi, alo;
      #pragma unroll
      for (int j = 0; j < 4; ++j) {
        unsigned u0 = __float_as_uint(a0[j]);
        ahi[j] = (short)(u0 >> 16);
        float r0 = a0[j] - __uint_as_float(u0 & 0xFFFF0000u);
        alo[j] = (short)(__float_as_uint(r0) >> 16);
        unsigned u1 = __float_as_uint(a1[j]);
        ahi[j + 4] = (short)(u1 >> 16);
        float r1 = a1[j] - __uint_as_float(u1 & 0xFFFF0000u);
        alo[j + 4] = (short)(__float_as_uint(r1) >> 16);
      }
      acc0 = __builtin_amdgcn_mfma_f32_16x16x32_bf16(ahi, w0h, acc0, 0, 0, 0);
      acc0 = __builtin_amdgcn_mfma_f32_16x16x32_bf16(ahi, w0l, acc0, 0, 0, 0);
      acc0 = __builtin_amdgcn_mfma_f32_16x16x32_bf16(alo, w0h, acc0, 0, 0, 0);
      acc1 = __builtin_amdgcn_mfma_f32_16x16x32_bf16(ahi, w1h, acc1, 0, 0, 0);
      acc1 = __builtin_amdgcn_mfma_f32_16x16x32_bf16(ahi, w1l, acc1, 0, 0, 0);
      acc1 = __builtin_amdgcn_mfma_f32_16x16x32_bf16(alo, w1h, acc1, 0, 0, 0);
    }
  }

  // ---- per-wave partials: valid C rows 0..3 live in lanes 0..15, regs 0..3
  // C/D layout: col = lane&15 (cout), row = (lane>>4)*4 + reg (voxel)
  if (lane < 16) {
    float* yp = Yp + (wv << 7);               // 4 v x 32 d per wave
    #pragma unroll
    for (int r = 0; r < 4; ++r) {
      yp[r * 32 + lane]      = acc0[r];
      yp[r * 32 + 16 + lane] = acc1[r];
    }
  }
  __syncthreads();

  // ---- reduce 8 wave-partials, normalize, bias, relu, store ----
  if (tid < EPW) {
    float s = 0.f;
    #pragma unroll
    for (int w = 0; w < 8; ++w) s += Yp[(w << 7) + tid];
    int v = tid >> 5;
    int d = tid & 31;
    float dn = fmaxf(den[v], 1e-8f);
    float y = s / dn + bias[d];
    out[(wg << 7) + tid] = fmaxf(y, 0.f);
  }
}

extern "C" void kernel_launch(void* const* d_in, const int* in_sizes, int n_in,
                              void* d_out, int out_size, void* d_ws, size_t ws_size,
                              hipStream_t stream) {
  const float* feats        = (const float*)d_in[0];
  const float* inp_points   = (const float*)d_in[1];
  const float* out_points   = (const float*)d_in[2];
  const float* out_extents  = (const float*)d_in[3];
  const float* scale_compat = (const float*)d_in[4];
  const int*   nbr_idx      = (const int*)d_in[5];
  const int*   row_splits   = (const int*)d_in[6];
  const float* nbr_dist     = (const float*)d_in[7];
  const float* W            = (const float*)d_in[8];
  const float* bias         = (const float*)d_in[9];

  u16*    wpk     = (u16*)d_ws;               // [4][64][64][8] u16 = 256 KiB
  __half* feats_h = (__half*)((char*)d_ws + 262144);
  const size_t ws_needed = 262144 + (size_t)FH_ELEMS * 2;   // ~17 MB
  const bool use_fp16 = (ws_size >= ws_needed);

  (void)hipFuncSetAttribute((const void*)cconv_kernel<true>,
                            hipFuncAttributeMaxDynamicSharedMemorySize,
                            SMEM_BYTES);
  (void)hipFuncSetAttribute((const void*)cconv_kernel<false>,
                            hipFuncAttributeMaxDynamicSharedMemorySize,
                            SMEM_BYTES);

  prep_w_kernel<<<512, 256, 0, stream>>>(W, wpk);
  if (use_fp16) {
    prep_f_kernel<<<FH_ELEMS / 4 / 256, 256, 0, stream>>>(feats, feats_h);
    cconv_kernel<true><<<NWG, THREADS, SMEM_BYTES, stream>>>(
        feats, feats_h, inp_points, out_points, out_extents, scale_compat,
        nbr_idx, row_splits, nbr_dist, bias, wpk, (float*)d_out);
  } else {
    cconv_kernel<false><<<NWG, THREADS, SMEM_BYTES, stream>>>(
        feats, feats_h, inp_points, out_points, out_extents, scale_compat,
        nbr_idx, row_splits, nbr_dist, bias, wpk, (float*)d_out);
  }
}

// Round 9
// 625.170 us; speedup vs baseline: 1.0439x; 1.0046x over previous
//
#include <hip/hip_runtime.h>
#include <hip/hip_bf16.h>

// Continuous convolution, single-pass fused design (round 9):
//   r6 shell (VX=4, 512 thr, 38KB LDS, 4 WG/CU) + fire-and-forget feats
//   gather: global_load_lds stages all 128 rows (16KB) into LDS overlaid on
//   the B-tile region BEFORE B is zeroed; threads then pull their 8 values
//   LDS->reg. Removes the r3-r8 latency chain (VGPR=28 => compiler
//   serialized register gathers; r2 proved the memory system sustains
//   ~500GB/s under request pressure while r3-r8 sat at ~310).
//   Contraction: bf16 hi/lo split MFMA (3 products) vs pre-packed W^T
//   fragment tables; B accum f32. fp16-feats experiment dropped (ws_size
//   too small; r8 silently took the fallback).

typedef unsigned short u16;
typedef unsigned int   u32;
typedef __attribute__((ext_vector_type(4))) float f32x4;
typedef __attribute__((ext_vector_type(8))) short short8;

#define NOUT    65536
#define VX      4               // voxels per WG
#define THREADS 512
#define EPW     128             // edges per WG
#define NWG     (NOUT / VX)     // 16384
#define BSTRIDE 2052            // f32 words per voxel (64 bins * 32 ch + 4 pad)
#define VROWB   (BSTRIDE * 4)   // 8208 bytes
#define BL_BYTES (VX * VROWB)   // 32832  (fstage [128][32] f32 overlays first 16KB)

// LDS carve (bytes):
#define OFF_W   BL_BYTES              // wls [8][128] f32  (alias Yp 4KB)
#define OFF_BCA (OFF_W + 8*EPW*4)     // bca [128] u32 (bb | mask<<16 | nc<<24)
#define OFF_FB  (OFF_BCA + EPW*4)     // fbase [128] int (feats word index)
#define OFF_DEN (OFF_FB + EPW*4)      // den [4] f32
#define SMEM_BYTES (OFF_DEN + 16)     // 37968 -> 4 WG/CU

// ---- prep: pack W (2048x32 f32) into MFMA B-fragment order, bf16 hi/lo ----
// wpk[tb][bin][lane][j] u16, tb: 0=hi d0-15, 1=lo d0-15, 2=hi d16-31, 3=lo.
// Lane l supplies B[kappa = bin*32 + (l>>4)*8 + j][d = (l&15) + 16*(tb>>1)].
__global__ void prep_w_kernel(const float* __restrict__ W,
                              u16* __restrict__ wpk) {
  int id  = blockIdx.x * 256 + threadIdx.x;   // 0..131071
  int j   = id & 7;
  int l   = (id >> 3) & 63;
  int bin = (id >> 9) & 63;
  int tb  = id >> 15;                         // 0..3
  int kap = (bin << 5) + ((l >> 4) << 3) + j;
  int d   = (l & 15) + ((tb >> 1) << 4);
  float w = W[kap * 32 + d];
  unsigned u = __float_as_uint(w);
  u16 val;
  if (tb & 1) {
    float rem = w - __uint_as_float(u & 0xFFFF0000u);   // exact residual
    val = (u16)(__float_as_uint(rem) >> 16);
  } else {
    val = (u16)(u >> 16);                               // truncated bf16
  }
  wpk[id] = val;
}

__launch_bounds__(THREADS, 8)   // VGPR<=64 so 4 WGs/CU fit wave slots
__global__ void cconv_kernel(const float* __restrict__ feats,
                             const float* __restrict__ inp_points,
                             const float* __restrict__ out_points,
                             const float* __restrict__ out_extents,
                             const float* __restrict__ scale_compat,
                             const int*   __restrict__ nbr_idx,
                             const int*   __restrict__ row_splits,
                             const float* __restrict__ nbr_dist,
                             const float* __restrict__ bias,
                             const u16*   __restrict__ wpk,
                             float*       __restrict__ out) {
  extern __shared__ __align__(16) char smem[];
  float* wls   = (float*)(smem + OFF_W);
  float* Yp    = wls;                         // alias after scatter done
  u32*   bca   = (u32*)(smem + OFF_BCA);
  int*   fbase = (int*)(smem + OFF_FB);
  float* den   = (float*)(smem + OFF_DEN);

  const int tid  = threadIdx.x;
  const int wg   = blockIdx.x;
  const int lane = tid & 63;
  const int wv   = tid >> 6;                  // wave 0..7

  // ---- geometry: one edge per thread (threads 0..127) ----
  if (tid < EPW) {
    const bool is64 = (row_splits[1] == 0);   // int32 view of int64 splits
    int e  = tid;
    int v  = e >> 5;
    int gv = (wg << 2) + v;
    int ge = (wg << 7) + e;
    int idx = nbr_idx[is64 ? (ge << 1) : ge];
    float dist = nbr_dist[ge];
    float sc   = scale_compat[ge];
    float om = 1.f - dist * dist;
    om = fminf(fmaxf(om, 0.f), 1.f);
    float a = sc * om * om * om;
    float inv = 2.f / out_extents[0];
    float ox = out_points[gv * 3 + 0];
    float oy = out_points[gv * 3 + 1];
    float oz = out_points[gv * 3 + 2];
    float rx = (inp_points[idx * 3 + 0] - ox) * inv;
    float ry = (inp_points[idx * 3 + 1] - oy) * inv;
    float rz = (inp_points[idx * 3 + 2] - oz) * inv;
    float n2   = sqrtf(rx * rx + ry * ry + rz * rz + 1e-12f);
    float ninf = fmaxf(fabsf(rx), fmaxf(fabsf(ry), fabsf(rz)));
    float scl  = (ninf > 1e-8f) ? (n2 / ninf) : 0.f;
    float cx = fminf(fmaxf(rx * scl, -1.f), 1.f);
    float cy = fminf(fmaxf(ry * scl, -1.f), 1.f);
    float cz = fminf(fmaxf(rz * scl, -1.f), 1.f);
    float ux = fminf(fmaxf((cx + 1.f) * 1.5f, 0.f), 3.f);
    float uy = fminf(fmaxf((cy + 1.f) * 1.5f, 0.f), 3.f);
    float uz = fminf(fmaxf((cz + 1.f) * 1.5f, 0.f), 3.f);
    float fx = fminf(floorf(ux), 2.f);
    float fy = fminf(floorf(uy), 2.f);
    float fz = fminf(floorf(uz), 2.f);
    float tx = ux - fx, ty = uy - fy, tz = uz - fz;
    int ix = (int)fx, iy = (int)fy, iz = (int)fz;
    float X1 = tx * a, X0 = a - X1;           // fold importance into x weights
    float Y1 = ty,     Y0 = 1.f - ty;
    float Z1 = tz,     Z0 = 1.f - tz;
    float p00 = X0 * Y0, p01 = X0 * Y1, p10 = X1 * Y0, p11 = X1 * Y1;
    float wc[8];
    wc[0] = p00 * Z0; wc[1] = p00 * Z1; wc[2] = p01 * Z0; wc[3] = p01 * Z1;
    wc[4] = p10 * Z0; wc[5] = p10 * Z1; wc[6] = p11 * Z0; wc[7] = p11 * Z1;
    int kb = (ix * 4 + iy) * 4 + iz;          // base bin (<=42)
    u32 bb = (u32)(v * VROWB + (kb << 7));    // < 32768
    int nc = 0; u32 mask = 0;
    #pragma unroll
    for (int k = 0; k < 8; ++k) {
      if (wc[k] != 0.f) {
        wls[nc * EPW + e] = wc[k];
        mask |= (1u << k);
        ++nc;
      }
    }
    bca[e]   = bb | (mask << 16) | ((u32)nc << 24);
    fbase[e] = idx << 5;                      // feats word index of row start
    // per-voxel denom: half-wave (32 lanes = 1 voxel) shuffle reduction
    float s = a;
    s += __shfl_xor(s, 1);
    s += __shfl_xor(s, 2);
    s += __shfl_xor(s, 4);
    s += __shfl_xor(s, 8);
    s += __shfl_xor(s, 16);
    if ((lane & 31) == 0) den[v] = s;
  }
  __syncthreads();

  // ---- stage all 128 feats rows into LDS (overlaying B region) ----
  // Chunk t (0..1023) = row r=t>>3, 16B piece k=t&7; dest byte = 16*t ->
  // row-major fstage[128][32] f32. Fire-and-forget: zero VGPR cost, all
  // 256 lines in flight per WG; __syncthreads drains vmcnt.
  {
    #pragma unroll
    for (int rd = 0; rd < 2; ++rd) {
      int t = (rd << 9) + tid;
      int r = t >> 3;
      int k = t & 7;
      const float* g = feats + fbase[r] + (k << 2);
      __builtin_amdgcn_global_load_lds(
          (const __attribute__((address_space(1))) void*)(const void*)g,
          (__attribute__((address_space(3))) void*)(void*)((float*)smem + (t << 2)),
          16, 0, 0);
    }
  }
  __syncthreads();   // stage complete

  // ---- pull this thread's 8 feats values LDS -> regs ----
  const int c  = tid & 31;                    // channel
  const int e0 = tid >> 5;                    // 0..15
  float fg[8];
  {
    const float* fs = (const float*)smem;
    #pragma unroll
    for (int it = 0; it < 8; ++it)            // banks: (e*32+c)&31 = c, 2-way
      fg[it] = fs[(((it << 4) + e0) << 5) + c];
  }
  __syncthreads();   // everyone done reading fstage

  // ---- zero B tile (all threads) ----
  {
    f32x4 z = {0.f, 0.f, 0.f, 0.f};
    for (int i = tid; i < (BL_BYTES / 16); i += THREADS)
      ((f32x4*)smem)[i] = z;
  }
  __syncthreads();

  // ---- scatter: lane=channel, half-wave=edge row ----
  {
    #pragma unroll
    for (int it = 0; it < 8; ++it) {
      int   e    = (it << 4) + e0;
      u32   m    = bca[e];
      u32   base = (m & 0xFFFFu) + ((u32)c << 2);
      u32   mask = (m >> 16) & 0xFFu;
      int   nc   = (int)(m >> 24);
      float f    = fg[it];
      for (int j = 0; j < nc; ++j) {          // ~2-3 iters, uniform per edge
        float w = wls[j * EPW + e];           // broadcast within half-wave
        int   k = __builtin_ctz(mask);
        mask &= mask - 1;
        u32 d = ((k & 1) << 7) | ((k & 2) << 8) | ((k & 4) << 9);
        atomicAdd((float*)(smem + base + d), w * f);  // banks 0..31, <=2-way
      }
    }
  }
  __syncthreads();

  // ---- MFMA contraction: wave wv owns bins [8*wv, 8*wv+8) ----
  f32x4 acc0 = {0.f, 0.f, 0.f, 0.f};          // cout 0..15
  f32x4 acc1 = {0.f, 0.f, 0.f, 0.f};          // cout 16..31
  {
    const short8* wp = (const short8*)wpk;    // [4][64][64] fragments
    int v16 = lane & 15;                      // A row (rows 4-15 dup of 0-3)
    int q   = lane >> 4;
    const char* arow = smem + (size_t)(v16 & 3) * VROWB;
    #pragma unroll
    for (int b = 0; b < 8; ++b) {
      int bin = (wv << 3) + b;
      // coalesced 1KB-burst B-fragment loads (L2-resident)
      short8 w0h = wp[((0 * 64 + bin) << 6) + lane];
      short8 w0l = wp[((1 * 64 + bin) << 6) + lane];
      short8 w1h = wp[((2 * 64 + bin) << 6) + lane];
      short8 w1l = wp[((3 * 64 + bin) << 6) + lane];
      const float* ap = (const float*)(arow + (bin << 7) + (q << 5));
      f32x4 a0 = *(const f32x4*)ap;           // ch k0..k0+3
      f32x4 a1 = *(const f32x4*)(ap + 4);     // ch k0+4..k0+7
      short8 ahi, alo;
      #pragma unroll
      for (int j = 0; j < 4; ++j) {
        unsigned u0 = __float_as_uint(a0[j]);
        ahi[j] = (short)(u0 >> 16);
        float r0 = a0[j] - __uint_as_float(u0 & 0xFFFF0000u);
        alo[j] = (short)(__float_as_uint(r0) >> 16);
        unsigned u1 = __float_as_uint(a1[j]);
        ahi[j + 4] = (short)(u1 >> 16);
        float r1 = a1[j] - __uint_as_float(u1 & 0xFFFF0000u);
        alo[j + 4] = (short)(__float_as_uint(r1) >> 16);
      }
      acc0 = __builtin_amdgcn_mfma_f32_16x16x32_bf16(ahi, w0h, acc0, 0, 0, 0);
      acc0 = __builtin_amdgcn_mfma_f32_16x16x32_bf16(ahi, w0l, acc0, 0, 0, 0);
      acc0 = __builtin_amdgcn_mfma_f32_16x16x32_bf16(alo, w0h, acc0, 0, 0, 0);
      acc1 = __builtin_amdgcn_mfma_f32_16x16x32_bf16(ahi, w1h, acc1, 0, 0, 0);
      acc1 = __builtin_amdgcn_mfma_f32_16x16x32_bf16(ahi, w1l, acc1, 0, 0, 0);
      acc1 = __builtin_amdgcn_mfma_f32_16x16x32_bf16(alo, w1h, acc1, 0, 0, 0);
    }
  }

  // ---- per-wave partials: valid C rows 0..3 live in lanes 0..15, regs 0..3
  // C/D layout: col = lane&15 (cout), row = (lane>>4)*4 + reg (voxel)
  if (lane < 16) {
    float* yp = Yp + (wv << 7);               // 4 v x 32 d per wave
    #pragma unroll
    for (int r = 0; r < 4; ++r) {
      yp[r * 32 + lane]      = acc0[r];
      yp[r * 32 + 16 + lane] = acc1[r];
    }
  }
  __syncthreads();

  // ---- reduce 8 wave-partials, normalize, bias, relu, store ----
  if (tid < EPW) {
    float s = 0.f;
    #pragma unroll
    for (int w = 0; w < 8; ++w) s += Yp[(w << 7) + tid];
    int v = tid >> 5;
    int d = tid & 31;
    float dn = fmaxf(den[v], 1e-8f);
    float y = s / dn + bias[d];
    out[(wg << 7) + tid] = fmaxf(y, 0.f);
  }
}

extern "C" void kernel_launch(void* const* d_in, const int* in_sizes, int n_in,
                              void* d_out, int out_size, void* d_ws, size_t ws_size,
                              hipStream_t stream) {
  const float* feats        = (const float*)d_in[0];
  const float* inp_points   = (const float*)d_in[1];
  const float* out_points   = (const float*)d_in[2];
  const float* out_extents  = (const float*)d_in[3];
  const float* scale_compat = (const float*)d_in[4];
  const int*   nbr_idx      = (const int*)d_in[5];
  const int*   row_splits   = (const int*)d_in[6];
  const float* nbr_dist     = (const float*)d_in[7];
  const float* W            = (const float*)d_in[8];
  const float* bias         = (const float*)d_in[9];

  u16* wpk = (u16*)d_ws;                // [4][64][64][8] u16 = 256 KiB

  static_assert(SMEM_BYTES <= 40960, "LDS over 4-per-CU budget");
  (void)hipFuncSetAttribute((const void*)cconv_kernel,
                            hipFuncAttributeMaxDynamicSharedMemorySize,
                            SMEM_BYTES);

  prep_w_kernel<<<512, 256, 0, stream>>>(W, wpk);
  cconv_kernel<<<NWG, THREADS, SMEM_BYTES, stream>>>(
      feats, inp_points, out_points, out_extents, scale_compat, nbr_idx,
      row_splits, nbr_dist, bias, wpk, (float*)d_out);
}